// Round 17
// baseline (336.538 us; speedup 1.0000x reference)
//
#include <hip/hip_runtime.h>
#include <cstdint>
#include <cstddef>

using bf16x8 = __attribute__((ext_vector_type(8))) short;
using f32x4  = __attribute__((ext_vector_type(4))) float;
using u32x4  = __attribute__((ext_vector_type(4))) unsigned int;

#define DI __device__ __forceinline__

// ADC quant on pre-scaled acc (= p/16 exact, weights +-1/16).
// |p|<=128 -> rint in [-8,8]; only +8 needs clamping. x16 folded into bn.
DI float pq3(float a) {
    return fminf(rintf(a), 7.f);
}
// fc variant on raw psum
DI float pq16(float ps) {
    return fminf(rintf(ps * 0.0625f), 7.f) * 16.f;
}

DI float bnv(float x, float g, float b, float m, float v) {
    return (x - m) * (g / sqrtf(v + 1e-5f)) + b;
}

DI unsigned short sgn_bf16(float v) {
    return (v >= 0.f) ? (unsigned short)0x3F80 : (unsigned short)0xBF80;
}

// ---------------- conv0 (full precision) + bn0 + sign -> bf16 NHWC ----------
__global__ __launch_bounds__(256)
void k_conv0(const float* __restrict__ x, const float* __restrict__ w,
             const float* __restrict__ bnp, unsigned short* __restrict__ out) {
    __shared__ float sX[3][3][36];
    const int b = blockIdx.x >> 5, y = blockIdx.x & 31;
    const int tid = threadIdx.x;
    const int o = tid & 127, xc = tid >> 7;

    for (int i = tid; i < 3 * 3 * 36; i += 256) {
        int col = i % 36, rr = (i / 36) % 3, c = i / 108;
        int gy = y + rr - 1, gx = col - 1;
        float v = 0.f;
        if ((unsigned)gy < 32u && (unsigned)gx < 32u)
            v = x[((b * 3 + c) * 32 + gy) * 32 + gx];
        sX[c][rr][col] = v;
    }
    float wr[27];
    const float* wp = w + o * 27;
    #pragma unroll
    for (int t = 0; t < 27; ++t) wr[t] = wp[t];
    __syncthreads();

    const float bg = bnp[o], bb = bnp[128 + o], bm = bnp[256 + o], bv = bnp[384 + o];
    unsigned short* op = out + ((size_t)(b * 32 + y) * 32) * 128 + o;

    #pragma unroll
    for (int q = 0; q < 4; ++q) {
        float acc0 = 0.f, acc1 = 0.f, acc2 = 0.f, acc3 = 0.f;
        const int X0 = xc * 16 + q * 4;
        #pragma unroll
        for (int c = 0; c < 3; ++c)
            #pragma unroll
            for (int ky = 0; ky < 3; ++ky) {
                float xv0 = sX[c][ky][X0 + 0], xv1 = sX[c][ky][X0 + 1];
                float xv2 = sX[c][ky][X0 + 2], xv3 = sX[c][ky][X0 + 3];
                float xv4 = sX[c][ky][X0 + 4], xv5 = sX[c][ky][X0 + 5];
                float w0 = wr[c * 9 + ky * 3 + 0];
                float w1 = wr[c * 9 + ky * 3 + 1];
                float w2 = wr[c * 9 + ky * 3 + 2];
                acc0 += xv0 * w0 + xv1 * w1 + xv2 * w2;
                acc1 += xv1 * w0 + xv2 * w1 + xv3 * w2;
                acc2 += xv2 * w0 + xv3 * w1 + xv4 * w2;
                acc3 += xv3 * w0 + xv4 * w1 + xv5 * w2;
            }
        op[(size_t)(X0 + 0) * 128] = sgn_bf16(bnv(acc0, bg, bb, bm, bv));
        op[(size_t)(X0 + 1) * 128] = sgn_bf16(bnv(acc1, bg, bb, bm, bv));
        op[(size_t)(X0 + 2) * 128] = sgn_bf16(bnv(acc2, bg, bb, bm, bv));
        op[(size_t)(X0 + 3) * 128] = sgn_bf16(bnv(acc3, bg, bb, bm, bv));
    }
}

// ---------------- weight pack: wpk2[g][tap10][chdw2][o][8c], values +-1/16 --
__global__ __launch_bounds__(256)
void k_pack_w2(const float* __restrict__ w, unsigned short* __restrict__ wpk,
               int Cin, int O, int G) {
    int idx = blockIdx.x * 256 + threadIdx.x;
    if (idx >= G * O * 160) return;
    int c8 = idx & 7;
    int o  = (idx >> 3) % O;
    int r2 = (idx >> 3) / O;
    int chdw = r2 & 1, tap = (r2 >> 1) % 10, g = r2 / 20;
    int c = chdw * 8 + c8, cg = g * 14 + c;
    unsigned short v = 0;
    if (tap < 9 && c < 14 && cg < Cin)
        v = (w[((size_t)o * Cin + cg) * 9 + tap] >= 0.f) ? (unsigned short)0x3D80
                                                         : (unsigned short)0xBD80;
    wpk[idx] = v;
}

// ---------------- MFMA crossbar conv, 2x2 wave decomp, group-pair phases ----
// Wave wv = (ms-pair mp=wv&1) x (o-half oh=wv>>1): 10 A-frags (LDS, rotated
// 48B slots) + 10 B-frags (global, wpk2 coalesced layout) -> 20 MFMA / group.
// TWO groups staged per barrier phase (buf0,buf1): 1 barrier per group.
// POOLMODE: 0 = bn+sign -> NHWC; 1 = pool+bn+sign -> NHWC (RW==16);
//           2 = pool+bn+sign -> a5p packed (RW==8, MS==4)
template <int H, int W, int Cin, int O, int G, int RH, int RW, int POOLMODE>
__global__ __launch_bounds__(256)
void k_conv_mfma(const unsigned int* __restrict__ act,
                 const char* __restrict__ wpk2,
                 const float* __restrict__ bnp,
                 unsigned short* __restrict__ outa,
                 unsigned short* __restrict__ a5p,
                 const unsigned int* __restrict__ zbuf) {
    constexpr int SH = RH + 2, SW = RW + 2;
    constexpr int MS = RH * RW / 16;
    constexpr int NREGX = W / RW;
    constexpr int SLOT8 = SH * SW * 8;
    constexpr int NST = (SLOT8 + 255) / 256;
    constexpr int BUF = SH * SW * 12;    // dwords per buffer
    static_assert(MS == 4, "2x2 decomposition needs MS==4");
    static_assert(POOLMODE != 1 || RW == 16, "pool mode 1 needs RW=16");
    static_assert(POOLMODE != 2 || RW == 8, "pool mode 2 needs 8x8");

    __shared__ __align__(16) unsigned int sA[2][BUF];

    const int tid  = threadIdx.x;
    const int regY = (int)blockIdx.x / NREGX, regX = (int)blockIdx.x % NREGX;
    const int o0   = blockIdx.y * 64;
    const int b    = blockIdx.z;

    const int lane = tid & 63, wv = tid >> 6;
    const int n  = lane & 15;
    const int kb = lane >> 4;
    const int hb = kb >> 1, ch = kb & 1;
    const int mp = wv & 1;          // ms-pair: ms = 2*mp + j
    const int oh = wv >> 1;         // o-half: o = o0 + oh*32 + hf*16 + n

    // hoisted staging descriptors: advance +7 dwords per staged group.
    // dst chunk rotation: dword cp -> ((cp>>2 + slot)%3)*4 + (cp&3)
    const unsigned int* sptr[NST];
    int sdst[NST];
    #pragma unroll
    for (int it = 0; it < NST; ++it) {
        int i = it * 256 + tid;
        sdst[it] = -1;
        if (i < SLOT8) {
            int cp = i & 7, slot = i >> 3;
            int yy = slot / SW, xx = slot - yy * SW;
            int gy = regY * RH + yy - 1, gx = regX * RW + xx - 1;
            sdst[it] = slot * 12 + (((cp >> 2) + slot) % 3) * 4 + (cp & 3);
            sptr[it] = ((unsigned)gy < (unsigned)H && (unsigned)gx < (unsigned)W)
                     ? act + ((size_t)(b * H + gy) * W + gx) * (Cin / 2) + cp
                     : zbuf + cp;
        }
    }

    // A read offsets (this wave's 2 ms), same rotation
    int offMS[2][5];
    #pragma unroll
    for (int j = 0; j < 2; ++j) {
        int p = (2 * mp + j) * 16 + n;
        int y = p / RW, x = p % RW;
        #pragma unroll
        for (int s = 0; s < 5; ++s) {
            int t = 2 * s + hb;
            int slotT = (t <= 8) ? ((y + t / 3) * SW + (x + t % 3)) : (y * SW + x);
            offMS[j][s] = slotT * 48 + ((ch + slotT) % 3) * 16;
        }
    }

    float tot[2][2][4];   // [ms j][o-half hf][r]
    #pragma unroll
    for (int j = 0; j < 2; ++j)
        #pragma unroll
        for (int hf = 0; hf < 2; ++hf)
            #pragma unroll
            for (int r = 0; r < 4; ++r) tot[j][hf][r] = 0.f;

    // B base (wpk2): (((g*10+tap)*2 + chdw)*O + o) * 16B; fold chdw=ch, o
    const char* wl = wpk2 + (size_t)(o0 + oh * 32 + n) * 16 + (size_t)ch * (O * 16);
    constexpr size_t WSTEP = (size_t)20 * O * 16;

    #pragma unroll 1
    for (int g = 0; g < G; g += 2) {
        const bool two = (g + 1 < G);
        // stage group g -> buf0
        {
            unsigned int* sb = &sA[0][0];
            #pragma unroll
            for (int it = 0; it < NST; ++it)
                if (sdst[it] >= 0) {
                    sb[sdst[it]] = *sptr[it];
                    sptr[it] += 7;
                }
        }
        // stage group g+1 -> buf1
        if (two) {
            unsigned int* sb = &sA[1][0];
            #pragma unroll
            for (int it = 0; it < NST; ++it)
                if (sdst[it] >= 0) {
                    sb[sdst[it]] = *sptr[it];
                    sptr[it] += 7;
                }
        }
        __syncthreads();

        #pragma unroll 1
        for (int u = 0; u < 2; ++u) {
            if (u == 1 && !two) break;
            bf16x8 bq[2][5];
            #pragma unroll
            for (int s = 0; s < 5; ++s) {
                const char* wt = wl + (size_t)(2 * s + hb) * (2 * O * 16);
                bq[0][s] = *(const bf16x8*)(wt);
                bq[1][s] = *(const bf16x8*)(wt + 256);
            }
            wl += WSTEP;

            const char* sAc = (const char*)&sA[u][0];
            #pragma unroll
            for (int j = 0; j < 2; ++j) {
                f32x4 a0 = {0.f, 0.f, 0.f, 0.f}, a1 = {0.f, 0.f, 0.f, 0.f};
                #pragma unroll
                for (int s = 0; s < 5; ++s) {
                    bf16x8 af = *(const bf16x8*)(sAc + offMS[j][s]);
                    a0 = __builtin_amdgcn_mfma_f32_16x16x32_bf16(af, bq[0][s], a0, 0, 0, 0);
                    a1 = __builtin_amdgcn_mfma_f32_16x16x32_bf16(af, bq[1][s], a1, 0, 0, 0);
                }
                #pragma unroll
                for (int r = 0; r < 4; ++r) {
                    tot[j][0][r] += pq3(a0[r]);
                    tot[j][1][r] += pq3(a1[r]);
                }
            }
        }
        __syncthreads();
    }

    // ---- epilogues (D: col = n, row m = 4*kb + r; global ms = 2*mp + j) ----
    #pragma unroll
    for (int hf = 0; hf < 2; ++hf) {
        const int oc = o0 + oh * 32 + hf * 16 + n;
        const float bg = bnp[oc], bb = bnp[O + oc], bm = bnp[2 * O + oc], bvr = bnp[3 * O + oc];

        if constexpr (POOLMODE == 0) {
            #pragma unroll
            for (int j = 0; j < 2; ++j)
                #pragma unroll
                for (int r = 0; r < 4; ++r) {
                    int p = (2 * mp + j) * 16 + 4 * kb + r;
                    int y = regY * RH + p / RW, x = regX * RW + p % RW;
                    float val = bnv(16.f * tot[j][hf][r], bg, bb, bm, bvr);
                    outa[(((size_t)b * H + y) * W + x) * O + oc] = sgn_bf16(val);
                }
        } else if constexpr (POOLMODE == 1) {
            #pragma unroll
            for (int q = 0; q < 2; ++q) {
                float v = fmaxf(fmaxf(tot[0][hf][2 * q], tot[0][hf][2 * q + 1]),
                                fmaxf(tot[1][hf][2 * q], tot[1][hf][2 * q + 1]));
                float val = bnv(16.f * v, bg, bb, bm, bvr);
                int py = regY * (RH / 2) + mp, px = regX * (RW / 2) + 2 * kb + q;
                outa[(((size_t)b * (H / 2) + py) * (W / 2) + px) * O + oc] = sgn_bf16(val);
            }
        } else {
            // RW=8: y = 2*ms + hb, x = 4*ch + r; vertical partner = lane ^ 32
            #pragma unroll
            for (int j = 0; j < 2; ++j)
                #pragma unroll
                for (int q = 0; q < 2; ++q) {
                    float h = fmaxf(tot[j][hf][2 * q], tot[j][hf][2 * q + 1]);
                    float o2 = __shfl_xor(h, 32);
                    float v = fmaxf(h, o2);
                    if (hb == 0) {
                        float val = bnv(16.f * v, bg, bb, bm, bvr);
                        int d = oc * 16 + (2 * mp + j) * 4 + 2 * ch + q;  // NCHW flatten
                        a5p[((size_t)(d >> 3) * 64 + b) * 8 + (d & 7)] = sgn_bf16(val);
                    }
                }
        }
    }
}

// ---------------- MFMA psum fc ----------------------------------------------
template <int D, int GPB>
__global__ __launch_bounds__(256)
void k_fc_mfma(const unsigned short* __restrict__ bpk, const float* __restrict__ w,
               float* __restrict__ accg) {
    const int lane = threadIdx.x & 63, wv = threadIdx.x >> 6;
    const int n = lane & 15, kb = lane >> 4;
    const int orow = blockIdx.x * 64 + wv * 16 + n;
    const int g0 = blockIdx.y * GPB;

    float tot[4][4];
    #pragma unroll
    for (int s = 0; s < 4; ++s)
        #pragma unroll
        for (int r = 0; r < 4; ++r) tot[s][r] = 0.f;

    #pragma unroll 1
    for (int g = 0; g < GPB; ++g) {
        const int kbase = (g0 + g) * 128;
        f32x4 a0 = {0,0,0,0}, a1 = {0,0,0,0}, a2 = {0,0,0,0}, a3 = {0,0,0,0};
        #pragma unroll
        for (int s = 0; s < 4; ++s) {
            const int k0 = kbase + s * 32 + kb * 8;
            const float* wp = w + (size_t)orow * D + k0;
            float4 wlo = *(const float4*)wp;
            float4 whi = *(const float4*)(wp + 4);
            bf16x8 af;
            af[0] = (short)sgn_bf16(wlo.x); af[1] = (short)sgn_bf16(wlo.y);
            af[2] = (short)sgn_bf16(wlo.z); af[3] = (short)sgn_bf16(wlo.w);
            af[4] = (short)sgn_bf16(whi.x); af[5] = (short)sgn_bf16(whi.y);
            af[6] = (short)sgn_bf16(whi.z); af[7] = (short)sgn_bf16(whi.w);
            const unsigned short* bp = bpk + (size_t)(k0 >> 3) * 512;
            bf16x8 b0 = *(const bf16x8*)(bp + (n +  0) * 8);
            bf16x8 b1 = *(const bf16x8*)(bp + (n + 16) * 8);
            bf16x8 b2 = *(const bf16x8*)(bp + (n + 32) * 8);
            bf16x8 b3 = *(const bf16x8*)(bp + (n + 48) * 8);
            a0 = __builtin_amdgcn_mfma_f32_16x16x32_bf16(af, b0, a0, 0, 0, 0);
            a1 = __builtin_amdgcn_mfma_f32_16x16x32_bf16(af, b1, a1, 0, 0, 0);
            a2 = __builtin_amdgcn_mfma_f32_16x16x32_bf16(af, b2, a2, 0, 0, 0);
            a3 = __builtin_amdgcn_mfma_f32_16x16x32_bf16(af, b3, a3, 0, 0, 0);
        }
        #pragma unroll
        for (int r = 0; r < 4; ++r) {
            tot[0][r] += pq16(a0[r]); tot[1][r] += pq16(a1[r]);
            tot[2][r] += pq16(a2[r]); tot[3][r] += pq16(a3[r]);
        }
    }
    const int od = blockIdx.x * 64 + wv * 16 + kb * 4;
    #pragma unroll
    for (int s = 0; s < 4; ++s)
        #pragma unroll
        for (int r = 0; r < 4; ++r)
            atomicAdd(&accg[(size_t)(od + r) * 64 + s * 16 + n], tot[s][r]);
}

template <bool SIGN>
__global__ __launch_bounds__(256)
void k_fc_ep(const float* __restrict__ accg, const float* __restrict__ bnp,
             unsigned short* __restrict__ packed, float* __restrict__ h2, int O) {
    int idx = blockIdx.x * 256 + threadIdx.x;
    int b = idx & 63, o = idx >> 6;
    float val = bnv(accg[idx], bnp[o], bnp[O + o], bnp[2 * O + o], bnp[3 * O + o]);
    if (SIGN) packed[((size_t)(o >> 3) * 64 + b) * 8 + (o & 7)] = sgn_bf16(val);
    else      h2[(size_t)b * 1024 + o] = val;
}

__global__ __launch_bounds__(64)
void k_out(const float* __restrict__ h2, const float* __restrict__ ow,
           const float* __restrict__ ob, const float* __restrict__ bnp,
           float* __restrict__ out) {
    int b = blockIdx.x / 10, o = blockIdx.x % 10;
    int lane = threadIdx.x;
    float acc = 0.f;
    #pragma unroll
    for (int i = 0; i < 16; ++i) {
        int k = i * 64 + lane;
        acc += h2[b * 1024 + k] * ow[o * 1024 + k];
    }
    #pragma unroll
    for (int off = 32; off; off >>= 1) acc += __shfl_xor(acc, off);
    if (lane == 0)
        out[b * 10 + o] = bnv(acc + ob[o], bnp[o], bnp[10 + o], bnp[20 + o], bnp[30 + o]);
}

extern "C" void kernel_launch(void* const* d_in, const int* in_sizes, int n_in,
                              void* d_out, int out_size, void* d_ws, size_t ws_size,
                              hipStream_t stream) {
    const float* x     = (const float*)d_in[0];
    const float* w0    = (const float*)d_in[1];
    const float* bn0   = (const float*)d_in[2];
    const float* w1    = (const float*)d_in[3];
    const float* bn1   = (const float*)d_in[4];
    const float* w2    = (const float*)d_in[5];
    const float* bn2   = (const float*)d_in[6];
    const float* w3    = (const float*)d_in[7];
    const float* bn3   = (const float*)d_in[8];
    const float* w4    = (const float*)d_in[9];
    const float* bn4   = (const float*)d_in[10];
    const float* w5    = (const float*)d_in[11];
    const float* bn5   = (const float*)d_in[12];
    const float* fc1w  = (const float*)d_in[13];
    const float* bnf1  = (const float*)d_in[14];
    const float* fc2w  = (const float*)d_in[15];
    const float* bnf2  = (const float*)d_in[16];
    const float* outw  = (const float*)d_in[17];
    const float* outb  = (const float*)d_in[18];
    const float* bnout = (const float*)d_in[19];

    char* ws = (char*)d_ws;
    unsigned short* actA  = (unsigned short*)(ws);              // 16,777,216 B
    unsigned short* actB  = (unsigned short*)(ws + 16777216);   //  4,194,304 B
    unsigned short* wpk   = (unsigned short*)(ws + 20971520);   //  6,291,456 B
    unsigned short* a5p   = (unsigned short*)(ws + 27262976);   //  1,048,576 B
    unsigned short* a6p   = (unsigned short*)(ws + 28311552);   //    131,072 B
    float*          h1acc = (float*)(ws + 28442624);            //    262,144 B
    float*          h2acc = (float*)(ws + 28704768);            //    262,144 B
    float*          h2    = (float*)(ws + 28966912);            //    262,144 B
    unsigned int*   zbuf  = (unsigned int*)(ws + 29229056);     //      4,096 B (zero page)

    const unsigned int* actA32 = (const unsigned int*)actA;
    const unsigned int* actB32 = (const unsigned int*)actB;
    const char* wpkc = (const char*)wpk;

    hipMemsetAsync(h1acc, 0, 262144, stream);
    hipMemsetAsync(h2acc, 0, 262144, stream);
    hipMemsetAsync(zbuf, 0, 4096, stream);

    // conv0 + bn0 + sign -> actA NHWC [64,32,32,128]
    k_conv0<<<dim3(2048), dim3(256), 0, stream>>>(x, w0, bn0, actA);

    // L1: 128->128 @32, pool fused -> actB NHWC [64,16,16,128]  (RH=4)
    k_pack_w2<<<dim3(800), dim3(256), 0, stream>>>(w1, wpk, 128, 128, 10);
    k_conv_mfma<32, 32, 128, 128, 10, 4, 16, 1>
        <<<dim3(16, 2, 64), dim3(256), 0, stream>>>(actA32, wpkc, bn1, actB, nullptr, zbuf);

    // L2: 128->256 @16 -> actA NHWC [64,16,16,256]  (RH=4)
    k_pack_w2<<<dim3(1600), dim3(256), 0, stream>>>(w2, wpk, 128, 256, 10);
    k_conv_mfma<16, 16, 128, 256, 10, 4, 16, 0>
        <<<dim3(4, 4, 64), dim3(256), 0, stream>>>(actB32, wpkc, bn2, actA, nullptr, zbuf);

    // L3: 256->256 @16, pool fused -> actB NHWC [64,8,8,256]  (RH=4)
    k_pack_w2<<<dim3(3040), dim3(256), 0, stream>>>(w3, wpk, 256, 256, 19);
    k_conv_mfma<16, 16, 256, 256, 19, 4, 16, 1>
        <<<dim3(4, 4, 64), dim3(256), 0, stream>>>(actA32, wpkc, bn3, actB, nullptr, zbuf);

    // L4: 256->512 @8 -> actA NHWC [64,8,8,512]
    k_pack_w2<<<dim3(6080), dim3(256), 0, stream>>>(w4, wpk, 256, 512, 19);
    k_conv_mfma<8, 8, 256, 512, 19, 8, 8, 0>
        <<<dim3(1, 8, 64), dim3(256), 0, stream>>>(actB32, wpkc, bn4, actA, nullptr, zbuf);

    // L5: 512->512 @8, pool -> a5p packed [8192][64]
    k_pack_w2<<<dim3(11840), dim3(256), 0, stream>>>(w5, wpk, 512, 512, 37);
    k_conv_mfma<8, 8, 512, 512, 37, 8, 8, 2>
        <<<dim3(1, 8, 64), dim3(256), 0, stream>>>(actA32, wpkc, bn5, nullptr, a5p, zbuf);

    // fc1 / fc2 / out
    k_fc_mfma<8192, 1><<<dim3(16, 64), dim3(256), 0, stream>>>(a5p, fc1w, h1acc);
    k_fc_ep<true><<<dim3(256), dim3(256), 0, stream>>>(h1acc, bnf1, a6p, nullptr, 1024);
    k_fc_mfma<1024, 1><<<dim3(16, 8), dim3(256), 0, stream>>>(a6p, fc2w, h2acc);
    k_fc_ep<false><<<dim3(256), dim3(256), 0, stream>>>(h2acc, bnf2, nullptr, h2, 1024);
    k_out<<<dim3(640), dim3(64), 0, stream>>>(h2, outw, outb, bnout, (float*)d_out);
}

// Round 18
// 265.153 us; speedup vs baseline: 1.2692x; 1.2692x over previous
//
#include <hip/hip_runtime.h>
#include <cstdint>
#include <cstddef>

using bf16x8 = __attribute__((ext_vector_type(8))) short;
using f32x4  = __attribute__((ext_vector_type(4))) float;
using u32x4  = __attribute__((ext_vector_type(4))) unsigned int;

#define DI __device__ __forceinline__

// ADC quant on pre-scaled acc (= p/16 exact, weights +-1/16).
// |p|<=128 -> rint in [-8,8]; only +8 needs clamping. x16 folded into bn.
DI float pq3(float a) {
    return fminf(rintf(a), 7.f);
}
// fc variant on raw psum
DI float pq16(float ps) {
    return fminf(rintf(ps * 0.0625f), 7.f) * 16.f;
}

DI float bnv(float x, float g, float b, float m, float v) {
    return (x - m) * (g / sqrtf(v + 1e-5f)) + b;
}

DI unsigned short sgn_bf16(float v) {
    return (v >= 0.f) ? (unsigned short)0x3F80 : (unsigned short)0xBF80;
}

// ---------------- conv0 (full precision) + bn0 + sign -> bf16 NHWC ----------
__global__ __launch_bounds__(256)
void k_conv0(const float* __restrict__ x, const float* __restrict__ w,
             const float* __restrict__ bnp, unsigned short* __restrict__ out) {
    __shared__ float sX[3][3][36];
    const int b = blockIdx.x >> 5, y = blockIdx.x & 31;
    const int tid = threadIdx.x;
    const int o = tid & 127, xc = tid >> 7;

    for (int i = tid; i < 3 * 3 * 36; i += 256) {
        int col = i % 36, rr = (i / 36) % 3, c = i / 108;
        int gy = y + rr - 1, gx = col - 1;
        float v = 0.f;
        if ((unsigned)gy < 32u && (unsigned)gx < 32u)
            v = x[((b * 3 + c) * 32 + gy) * 32 + gx];
        sX[c][rr][col] = v;
    }
    float wr[27];
    const float* wp = w + o * 27;
    #pragma unroll
    for (int t = 0; t < 27; ++t) wr[t] = wp[t];
    __syncthreads();

    const float bg = bnp[o], bb = bnp[128 + o], bm = bnp[256 + o], bv = bnp[384 + o];
    unsigned short* op = out + ((size_t)(b * 32 + y) * 32) * 128 + o;

    #pragma unroll
    for (int q = 0; q < 4; ++q) {
        float acc0 = 0.f, acc1 = 0.f, acc2 = 0.f, acc3 = 0.f;
        const int X0 = xc * 16 + q * 4;
        #pragma unroll
        for (int c = 0; c < 3; ++c)
            #pragma unroll
            for (int ky = 0; ky < 3; ++ky) {
                float xv0 = sX[c][ky][X0 + 0], xv1 = sX[c][ky][X0 + 1];
                float xv2 = sX[c][ky][X0 + 2], xv3 = sX[c][ky][X0 + 3];
                float xv4 = sX[c][ky][X0 + 4], xv5 = sX[c][ky][X0 + 5];
                float w0 = wr[c * 9 + ky * 3 + 0];
                float w1 = wr[c * 9 + ky * 3 + 1];
                float w2 = wr[c * 9 + ky * 3 + 2];
                acc0 += xv0 * w0 + xv1 * w1 + xv2 * w2;
                acc1 += xv1 * w0 + xv2 * w1 + xv3 * w2;
                acc2 += xv2 * w0 + xv3 * w1 + xv4 * w2;
                acc3 += xv3 * w0 + xv4 * w1 + xv5 * w2;
            }
        op[(size_t)(X0 + 0) * 128] = sgn_bf16(bnv(acc0, bg, bb, bm, bv));
        op[(size_t)(X0 + 1) * 128] = sgn_bf16(bnv(acc1, bg, bb, bm, bv));
        op[(size_t)(X0 + 2) * 128] = sgn_bf16(bnv(acc2, bg, bb, bm, bv));
        op[(size_t)(X0 + 3) * 128] = sgn_bf16(bnv(acc3, bg, bb, bm, bv));
    }
}

// ---------------- weight pack: wpk2[g][tap10][chdw2][o][8c], values +-1/16 --
__global__ __launch_bounds__(256)
void k_pack_w2(const float* __restrict__ w, unsigned short* __restrict__ wpk,
               int Cin, int O, int G) {
    int idx = blockIdx.x * 256 + threadIdx.x;
    if (idx >= G * O * 160) return;
    int c8 = idx & 7;
    int o  = (idx >> 3) % O;
    int r2 = (idx >> 3) / O;
    int chdw = r2 & 1, tap = (r2 >> 1) % 10, g = r2 / 20;
    int c = chdw * 8 + c8, cg = g * 14 + c;
    unsigned short v = 0;
    if (tap < 9 && c < 14 && cg < Cin)
        v = (w[((size_t)o * Cin + cg) * 9 + tap] >= 0.f) ? (unsigned short)0x3D80
                                                         : (unsigned short)0xBD80;
    wpk[idx] = v;
}

// ---------------- MFMA crossbar conv, 2x2 wave decomposition ----------------
// Wave wv = (ms-pair mp=wv&1) x (o-chunk oh=wv>>1). OT = o per block (64|32).
// Per wave/group: 10 A-frags (LDS, rotated 48B slots) + 5*NHF B-frags (global,
// wpk2 coalesced) -> 10*NHF MFMAs.  NHF = OT/32 (16-o chunks per wave).
// POOLMODE: 0 = bn+sign -> NHWC; 1 = pool+bn+sign -> NHWC (RW==16);
//           2 = pool+bn+sign -> a5p packed (RW==8, MS==4)
template <int H, int W, int Cin, int O, int G, int RH, int RW, int POOLMODE, int OT>
__global__ __launch_bounds__(256)
void k_conv_mfma(const unsigned int* __restrict__ act,
                 const char* __restrict__ wpk2,
                 const float* __restrict__ bnp,
                 unsigned short* __restrict__ outa,
                 unsigned short* __restrict__ a5p,
                 const unsigned int* __restrict__ zbuf) {
    constexpr int SH = RH + 2, SW = RW + 2;
    constexpr int MS = RH * RW / 16;
    constexpr int NREGX = W / RW;
    constexpr int SLOT8 = SH * SW * 8;
    constexpr int NST = (SLOT8 + 255) / 256;
    constexpr int NHF = OT / 32;        // 16-o chunks per wave (1 or 2)
    static_assert(MS == 4, "2x2 decomposition needs MS==4");
    static_assert(OT == 64 || OT == 32, "OT must be 64 or 32");
    static_assert(POOLMODE != 1 || RW == 16, "pool mode 1 needs RW=16");
    static_assert(POOLMODE != 2 || RW == 8, "pool mode 2 needs 8x8");

    __shared__ __align__(16) unsigned int sA[SH * SW * 12];

    const int tid  = threadIdx.x;
    const int regY = (int)blockIdx.x / NREGX, regX = (int)blockIdx.x % NREGX;
    const int o0   = blockIdx.y * OT;
    const int b    = blockIdx.z;

    const int lane = tid & 63, wv = tid >> 6;
    const int n  = lane & 15;
    const int kb = lane >> 4;
    const int hb = kb >> 1, ch = kb & 1;
    const int mp = wv & 1;          // ms-pair: ms = 2*mp + j
    const int oh = wv >> 1;         // o-chunk: o = o0 + oh*(OT/2) + hf*16 + n

    // hoisted staging descriptors: advance +7 dwords per group.
    // dst chunk rotation: dword cp -> ((cp>>2 + slot)%3)*4 + (cp&3)
    const unsigned int* sptr[NST];
    int sdst[NST];
    #pragma unroll
    for (int it = 0; it < NST; ++it) {
        int i = it * 256 + tid;
        sdst[it] = -1;
        if (i < SLOT8) {
            int cp = i & 7, slot = i >> 3;
            int yy = slot / SW, xx = slot - yy * SW;
            int gy = regY * RH + yy - 1, gx = regX * RW + xx - 1;
            sdst[it] = slot * 12 + (((cp >> 2) + slot) % 3) * 4 + (cp & 3);
            sptr[it] = ((unsigned)gy < (unsigned)H && (unsigned)gx < (unsigned)W)
                     ? act + ((size_t)(b * H + gy) * W + gx) * (Cin / 2) + cp
                     : zbuf + cp;
        }
    }

    // A read offsets (this wave's 2 ms), same rotation
    int offMS[2][5];
    #pragma unroll
    for (int j = 0; j < 2; ++j) {
        int p = (2 * mp + j) * 16 + n;
        int y = p / RW, x = p % RW;
        #pragma unroll
        for (int s = 0; s < 5; ++s) {
            int t = 2 * s + hb;
            int slotT = (t <= 8) ? ((y + t / 3) * SW + (x + t % 3)) : (y * SW + x);
            offMS[j][s] = slotT * 48 + ((ch + slotT) % 3) * 16;
        }
    }

    float tot[2][NHF][4];   // [ms j][o-chunk hf][r]
    #pragma unroll
    for (int j = 0; j < 2; ++j)
        #pragma unroll
        for (int hf = 0; hf < NHF; ++hf)
            #pragma unroll
            for (int r = 0; r < 4; ++r) tot[j][hf][r] = 0.f;

    // B base (wpk2): (((g*10+tap)*2 + chdw)*O + o) * 16B; fold chdw=ch, o
    const char* wl = wpk2 + (size_t)(o0 + oh * (OT / 2) + n) * 16 + (size_t)ch * (O * 16);

    #pragma unroll 1
    for (int g = 0; g < G; ++g) {
        #pragma unroll
        for (int it = 0; it < NST; ++it)
            if (sdst[it] >= 0) {
                sA[sdst[it]] = *sptr[it];
                sptr[it] += 7;
            }
        bf16x8 bq[NHF][5];
        #pragma unroll
        for (int s = 0; s < 5; ++s) {
            const char* wt = wl + (size_t)(2 * s + hb) * (2 * O * 16);
            #pragma unroll
            for (int hf = 0; hf < NHF; ++hf)
                bq[hf][s] = *(const bf16x8*)(wt + hf * 256);
        }
        wl += (size_t)20 * O * 16;
        __syncthreads();

        const char* sAc = (const char*)sA;
        #pragma unroll
        for (int j = 0; j < 2; ++j) {
            f32x4 acc[NHF];
            #pragma unroll
            for (int hf = 0; hf < NHF; ++hf) acc[hf] = (f32x4){0.f, 0.f, 0.f, 0.f};
            #pragma unroll
            for (int s = 0; s < 5; ++s) {
                bf16x8 af = *(const bf16x8*)(sAc + offMS[j][s]);
                #pragma unroll
                for (int hf = 0; hf < NHF; ++hf)
                    acc[hf] = __builtin_amdgcn_mfma_f32_16x16x32_bf16(af, bq[hf][s], acc[hf], 0, 0, 0);
            }
            #pragma unroll
            for (int hf = 0; hf < NHF; ++hf)
                #pragma unroll
                for (int r = 0; r < 4; ++r)
                    tot[j][hf][r] += pq3(acc[hf][r]);
        }
        __syncthreads();
    }

    // ---- epilogues (D: col = n, row m = 4*kb + r; global ms = 2*mp + j) ----
    #pragma unroll
    for (int hf = 0; hf < NHF; ++hf) {
        const int oc = o0 + oh * (OT / 2) + hf * 16 + n;
        const float bg = bnp[oc], bb = bnp[O + oc], bm = bnp[2 * O + oc], bvr = bnp[3 * O + oc];

        if constexpr (POOLMODE == 0) {
            #pragma unroll
            for (int j = 0; j < 2; ++j)
                #pragma unroll
                for (int r = 0; r < 4; ++r) {
                    int p = (2 * mp + j) * 16 + 4 * kb + r;
                    int y = regY * RH + p / RW, x = regX * RW + p % RW;
                    float val = bnv(16.f * tot[j][hf][r], bg, bb, bm, bvr);
                    outa[(((size_t)b * H + y) * W + x) * O + oc] = sgn_bf16(val);
                }
        } else if constexpr (POOLMODE == 1) {
            #pragma unroll
            for (int q = 0; q < 2; ++q) {
                float v = fmaxf(fmaxf(tot[0][hf][2 * q], tot[0][hf][2 * q + 1]),
                                fmaxf(tot[1][hf][2 * q], tot[1][hf][2 * q + 1]));
                float val = bnv(16.f * v, bg, bb, bm, bvr);
                int py = regY * (RH / 2) + mp, px = regX * (RW / 2) + 2 * kb + q;
                outa[(((size_t)b * (H / 2) + py) * (W / 2) + px) * O + oc] = sgn_bf16(val);
            }
        } else {
            // RW=8: y = 2*ms + hb, x = 4*ch + r; vertical partner = lane ^ 32
            #pragma unroll
            for (int j = 0; j < 2; ++j)
                #pragma unroll
                for (int q = 0; q < 2; ++q) {
                    float h = fmaxf(tot[j][hf][2 * q], tot[j][hf][2 * q + 1]);
                    float o2 = __shfl_xor(h, 32);
                    float v = fmaxf(h, o2);
                    if (hb == 0) {
                        float val = bnv(16.f * v, bg, bb, bm, bvr);
                        int d = oc * 16 + (2 * mp + j) * 4 + 2 * ch + q;  // NCHW flatten
                        a5p[((size_t)(d >> 3) * 64 + b) * 8 + (d & 7)] = sgn_bf16(val);
                    }
                }
        }
    }
}

// ---------------- MFMA psum fc ----------------------------------------------
template <int D, int GPB>
__global__ __launch_bounds__(256)
void k_fc_mfma(const unsigned short* __restrict__ bpk, const float* __restrict__ w,
               float* __restrict__ accg) {
    const int lane = threadIdx.x & 63, wv = threadIdx.x >> 6;
    const int n = lane & 15, kb = lane >> 4;
    const int orow = blockIdx.x * 64 + wv * 16 + n;
    const int g0 = blockIdx.y * GPB;

    float tot[4][4];
    #pragma unroll
    for (int s = 0; s < 4; ++s)
        #pragma unroll
        for (int r = 0; r < 4; ++r) tot[s][r] = 0.f;

    #pragma unroll 1
    for (int g = 0; g < GPB; ++g) {
        const int kbase = (g0 + g) * 128;
        f32x4 a0 = {0,0,0,0}, a1 = {0,0,0,0}, a2 = {0,0,0,0}, a3 = {0,0,0,0};
        #pragma unroll
        for (int s = 0; s < 4; ++s) {
            const int k0 = kbase + s * 32 + kb * 8;
            const float* wp = w + (size_t)orow * D + k0;
            float4 wlo = *(const float4*)wp;
            float4 whi = *(const float4*)(wp + 4);
            bf16x8 af;
            af[0] = (short)sgn_bf16(wlo.x); af[1] = (short)sgn_bf16(wlo.y);
            af[2] = (short)sgn_bf16(wlo.z); af[3] = (short)sgn_bf16(wlo.w);
            af[4] = (short)sgn_bf16(whi.x); af[5] = (short)sgn_bf16(whi.y);
            af[6] = (short)sgn_bf16(whi.z); af[7] = (short)sgn_bf16(whi.w);
            const unsigned short* bp = bpk + (size_t)(k0 >> 3) * 512;
            bf16x8 b0 = *(const bf16x8*)(bp + (n +  0) * 8);
            bf16x8 b1 = *(const bf16x8*)(bp + (n + 16) * 8);
            bf16x8 b2 = *(const bf16x8*)(bp + (n + 32) * 8);
            bf16x8 b3 = *(const bf16x8*)(bp + (n + 48) * 8);
            a0 = __builtin_amdgcn_mfma_f32_16x16x32_bf16(af, b0, a0, 0, 0, 0);
            a1 = __builtin_amdgcn_mfma_f32_16x16x32_bf16(af, b1, a1, 0, 0, 0);
            a2 = __builtin_amdgcn_mfma_f32_16x16x32_bf16(af, b2, a2, 0, 0, 0);
            a3 = __builtin_amdgcn_mfma_f32_16x16x32_bf16(af, b3, a3, 0, 0, 0);
        }
        #pragma unroll
        for (int r = 0; r < 4; ++r) {
            tot[0][r] += pq16(a0[r]); tot[1][r] += pq16(a1[r]);
            tot[2][r] += pq16(a2[r]); tot[3][r] += pq16(a3[r]);
        }
    }
    const int od = blockIdx.x * 64 + wv * 16 + kb * 4;
    #pragma unroll
    for (int s = 0; s < 4; ++s)
        #pragma unroll
        for (int r = 0; r < 4; ++r)
            atomicAdd(&accg[(size_t)(od + r) * 64 + s * 16 + n], tot[s][r]);
}

template <bool SIGN>
__global__ __launch_bounds__(256)
void k_fc_ep(const float* __restrict__ accg, const float* __restrict__ bnp,
             unsigned short* __restrict__ packed, float* __restrict__ h2, int O) {
    int idx = blockIdx.x * 256 + threadIdx.x;
    int b = idx & 63, o = idx >> 6;
    float val = bnv(accg[idx], bnp[o], bnp[O + o], bnp[2 * O + o], bnp[3 * O + o]);
    if (SIGN) packed[((size_t)(o >> 3) * 64 + b) * 8 + (o & 7)] = sgn_bf16(val);
    else      h2[(size_t)b * 1024 + o] = val;
}

__global__ __launch_bounds__(64)
void k_out(const float* __restrict__ h2, const float* __restrict__ ow,
           const float* __restrict__ ob, const float* __restrict__ bnp,
           float* __restrict__ out) {
    int b = blockIdx.x / 10, o = blockIdx.x % 10;
    int lane = threadIdx.x;
    float acc = 0.f;
    #pragma unroll
    for (int i = 0; i < 16; ++i) {
        int k = i * 64 + lane;
        acc += h2[b * 1024 + k] * ow[o * 1024 + k];
    }
    #pragma unroll
    for (int off = 32; off; off >>= 1) acc += __shfl_xor(acc, off);
    if (lane == 0)
        out[b * 10 + o] = bnv(acc + ob[o], bnp[o], bnp[10 + o], bnp[20 + o], bnp[30 + o]);
}

extern "C" void kernel_launch(void* const* d_in, const int* in_sizes, int n_in,
                              void* d_out, int out_size, void* d_ws, size_t ws_size,
                              hipStream_t stream) {
    const float* x     = (const float*)d_in[0];
    const float* w0    = (const float*)d_in[1];
    const float* bn0   = (const float*)d_in[2];
    const float* w1    = (const float*)d_in[3];
    const float* bn1   = (const float*)d_in[4];
    const float* w2    = (const float*)d_in[5];
    const float* bn2   = (const float*)d_in[6];
    const float* w3    = (const float*)d_in[7];
    const float* bn3   = (const float*)d_in[8];
    const float* w4    = (const float*)d_in[9];
    const float* bn4   = (const float*)d_in[10];
    const float* w5    = (const float*)d_in[11];
    const float* bn5   = (const float*)d_in[12];
    const float* fc1w  = (const float*)d_in[13];
    const float* bnf1  = (const float*)d_in[14];
    const float* fc2w  = (const float*)d_in[15];
    const float* bnf2  = (const float*)d_in[16];
    const float* outw  = (const float*)d_in[17];
    const float* outb  = (const float*)d_in[18];
    const float* bnout = (const float*)d_in[19];

    char* ws = (char*)d_ws;
    unsigned short* actA  = (unsigned short*)(ws);              // 16,777,216 B
    unsigned short* actB  = (unsigned short*)(ws + 16777216);   //  4,194,304 B
    unsigned short* wpk   = (unsigned short*)(ws + 20971520);   //  6,291,456 B
    unsigned short* a5p   = (unsigned short*)(ws + 27262976);   //  1,048,576 B
    unsigned short* a6p   = (unsigned short*)(ws + 28311552);   //    131,072 B
    float*          h1acc = (float*)(ws + 28442624);            //    262,144 B
    float*          h2acc = (float*)(ws + 28704768);            //    262,144 B
    float*          h2    = (float*)(ws + 28966912);            //    262,144 B
    unsigned int*   zbuf  = (unsigned int*)(ws + 29229056);     //      4,096 B (zero page)

    const unsigned int* actA32 = (const unsigned int*)actA;
    const unsigned int* actB32 = (const unsigned int*)actB;
    const char* wpkc = (const char*)wpk;

    hipMemsetAsync(h1acc, 0, 262144, stream);
    hipMemsetAsync(h2acc, 0, 262144, stream);
    hipMemsetAsync(zbuf, 0, 4096, stream);

    // conv0 + bn0 + sign -> actA NHWC [64,32,32,128]
    k_conv0<<<dim3(2048), dim3(256), 0, stream>>>(x, w0, bn0, actA);

    // L1: 128->128 @32, pool fused -> actB NHWC [64,16,16,128]  (RH=4, OT=64)
    k_pack_w2<<<dim3(800), dim3(256), 0, stream>>>(w1, wpk, 128, 128, 10);
    k_conv_mfma<32, 32, 128, 128, 10, 4, 16, 1, 64>
        <<<dim3(16, 2, 64), dim3(256), 0, stream>>>(actA32, wpkc, bn1, actB, nullptr, zbuf);

    // L2: 128->256 @16 -> actA NHWC [64,16,16,256]  (RH=4, OT=64)
    k_pack_w2<<<dim3(1600), dim3(256), 0, stream>>>(w2, wpk, 128, 256, 10);
    k_conv_mfma<16, 16, 128, 256, 10, 4, 16, 0, 64>
        <<<dim3(4, 4, 64), dim3(256), 0, stream>>>(actB32, wpkc, bn2, actA, nullptr, zbuf);

    // L3: 256->256 @16, pool fused -> actB NHWC [64,8,8,256]  (RH=4, OT=64)
    k_pack_w2<<<dim3(3040), dim3(256), 0, stream>>>(w3, wpk, 256, 256, 19);
    k_conv_mfma<16, 16, 256, 256, 19, 4, 16, 1, 64>
        <<<dim3(4, 4, 64), dim3(256), 0, stream>>>(actA32, wpkc, bn3, actB, nullptr, zbuf);

    // L4: 256->512 @8 -> actA NHWC [64,8,8,512]  (OT=32, 1024 blocks)
    k_pack_w2<<<dim3(6080), dim3(256), 0, stream>>>(w4, wpk, 256, 512, 19);
    k_conv_mfma<8, 8, 256, 512, 19, 8, 8, 0, 32>
        <<<dim3(1, 16, 64), dim3(256), 0, stream>>>(actB32, wpkc, bn4, actA, nullptr, zbuf);

    // L5: 512->512 @8, pool -> a5p packed [8192][64]  (OT=32, 1024 blocks)
    k_pack_w2<<<dim3(11840), dim3(256), 0, stream>>>(w5, wpk, 512, 512, 37);
    k_conv_mfma<8, 8, 512, 512, 37, 8, 8, 2, 32>
        <<<dim3(1, 16, 64), dim3(256), 0, stream>>>(actA32, wpkc, bn5, nullptr, a5p, zbuf);

    // fc1 / fc2 / out
    k_fc_mfma<8192, 1><<<dim3(16, 64), dim3(256), 0, stream>>>(a5p, fc1w, h1acc);
    k_fc_ep<true><<<dim3(256), dim3(256), 0, stream>>>(h1acc, bnf1, a6p, nullptr, 1024);
    k_fc_mfma<1024, 1><<<dim3(16, 8), dim3(256), 0, stream>>>(a6p, fc2w, h2acc);
    k_fc_ep<false><<<dim3(256), dim3(256), 0, stream>>>(h2acc, bnf2, nullptr, h2, 1024);
    k_out<<<dim3(640), dim3(64), 0, stream>>>(h2, outw, outb, bnout, (float*)d_out);
}